// Round 12
// baseline (2141.833 us; speedup 1.0000x reference)
//
#include <hip/hip_runtime.h>

typedef unsigned short u16;
typedef unsigned int u32;
typedef __attribute__((ext_vector_type(4))) float f32x4;
typedef __attribute__((ext_vector_type(8))) short bf16x8;
typedef __attribute__((ext_vector_type(4))) u16 u16x4;
typedef __attribute__((ext_vector_type(8))) u16 u16x8;

#define B_ 16
#define N_ 1024
#define D_ 1024
#define BM 256
#define BN 256
#define BK 64

__device__ __forceinline__ float bf2f(u16 v) {
  return __uint_as_float((u32)v << 16);
}
__device__ __forceinline__ u16 f2bf(float f) {
  u32 u = __float_as_uint(f);
  return (u16)((u + 0x7FFFu + ((u >> 16) & 1u)) >> 16);
}
__device__ __forceinline__ void gload_lds16(const void* g, void* l) {
  __builtin_amdgcn_global_load_lds(
      (const __attribute__((address_space(1))) void*)g,
      (__attribute__((address_space(3))) void*)l, 16, 0, 0);
}

// ---------------- merged cast: x (fp32->bf16) + 4 weights -> contiguous ----
__global__ __launch_bounds__(256) void cast_all(
    const float* __restrict__ x, const float* __restrict__ w0,
    const float* __restrict__ w1, const float* __restrict__ w2,
    const float* __restrict__ w3, u16* __restrict__ outx,
    u16* __restrict__ outw) {
  const int nx4 = (B_ * N_ * D_) / 4;          // 4M float4
  const int per = (D_ * D_) / 4;               // 256K float4 per weight
  const int tot = nx4 + 4 * per;
  const int stride = gridDim.x * blockDim.x;
  for (int i = blockIdx.x * blockDim.x + threadIdx.x; i < tot; i += stride) {
    float4 v;
    u16x4* dst;
    if (i < nx4) {
      v = ((const float4*)x)[i];
      dst = (u16x4*)outx + i;
    } else {
      const int k = i - nx4;
      const int w = k / per, r = k - w * per;
      const float* src = (w == 0) ? w0 : (w == 1) ? w1 : (w == 2) ? w2 : w3;
      v = ((const float4*)src)[r];
      dst = (u16x4*)outw + k;
    }
    u16x4 o;
    o[0] = f2bf(v.x); o[1] = f2bf(v.y); o[2] = f2bf(v.z); o[3] = f2bf(v.w);
    *dst = o;
  }
}

// ---------------- 256x256 8-wave bt-GEMM, 4 phases / 4 barriers per K-tile --
// C[i,j] = sum_k A[i,k]*B[j,k], K fixed = 1024 (16 K-tiles of BK=64).
// LDS: [region A0,A1,B0,B1 x 32KB][buf x 16KB]. Swizzle byte^=((row&7)<<4);
// kk half-select XOR-folded into precomputed base pointers (NEVER added —
// the R7-R9 NaN bug). Sync: barrier first, lgkmcnt(0) after (m201
// semantics); overwrite ledger as R11. Gate vmcnt(4) once per tile at P4.
// R12: coalesced LDS-bounce epilogue (padded f32[32][264] scratch, b128
// reads, 256B-contiguous stores per 16-lane group).
template <typename OutT, bool SPLITC>
__global__ __launch_bounds__(512, 2) void gemm_bt256(
    const u16* __restrict__ A, const u16* __restrict__ Bm, OutT* __restrict__ C,
    long long sA, long long sB, long long sC, int tx_n, int nb_per) {
  __shared__ u16 lds[4][2][128 * 64];  // [A0,A1,B0,B1][buf]
  const int tid = threadIdx.x;
  const int lane = tid & 63;
  const int wid = tid >> 6;
  const int wm = wid >> 2;   // 0..1 -> 128-row half
  const int wn = wid & 3;    // 0..3 -> 64-col group
  const int rl = lane & 15, kl = lane >> 4;

  // bijective XCD swizzle (nwg % 8 == 0 for all our grids)
  const int nwg = gridDim.x;
  const int orig = blockIdx.x;
  const int wgid = (orig & 7) * (nwg >> 3) + (orig >> 3);
  const int batch = wgid / nb_per;
  const int rem = wgid % nb_per;
  const int row0 = (rem / tx_n) * BM;
  const int col0 = (rem % tx_n) * BN;
  A += (long long)batch * sA;
  Bm += (long long)batch * sB;
  OutT* Cb;
  if constexpr (SPLITC) {
    Cb = C + (size_t)(col0 >> 10) * ((size_t)16384 * 1024) + (col0 & 1023);
  } else {
    Cb = C + (long long)batch * sC + col0;
  }

  const char* lb = (const char*)&lds[0][0][0];
  char* lwt = (char*)&lds[0][0][0] + tid * 16;

  // kk-resolved swizzled read bases (XOR fold, see header comment)
  const u32 mask = (u32)((rl & 7) << 4);
  const u32 cs0 = ((u32)(kl * 16)) ^ mask;        // kk=0 column bytes
  const u32 cs1 = ((u32)(64 + kl * 16)) ^ mask;   // kk=1 column bytes
  const char* pAk0 = lb + wm * 32768 + rl * 128 + cs0;
  const char* pAk1 = lb + wm * 32768 + rl * 128 + cs1;
  const char* pBk0 =
      lb + (2 + (wn >> 1)) * 32768 + (wn & 1) * 8192 + rl * 128 + cs0;
  const char* pBk1 =
      lb + (2 + (wn >> 1)) * 32768 + (wn & 1) * 8192 + rl * 128 + cs1;
#define RDA(BUF, MI, KK) \
  (*(const bf16x8*)(((KK) ? pAk1 : pAk0) + (BUF)*16384 + (MI)*2048))
#define RDB(BUF, NI, KK) \
  (*(const bf16x8*)(((KK) ? pBk1 : pBk0) + (BUF)*16384 + (NI)*2048))

  // staging: linear LDS dest, inverse-swizzled global source
  const int r0 = tid >> 3;
  const u32 li0 = (u32)(((tid & 7) * 16) ^ ((r0 & 7) << 4));
  const u16* gA0 = A + (size_t)(row0 + r0) * 1024 + (li0 >> 1);
  const u16* gB0 = Bm + (size_t)(col0 + r0) * 1024 + (li0 >> 1);
#define STAGE_A(H, BUF, T)                                                    \
  do {                                                                        \
    gload_lds16(gA0 + (size_t)((H)*128 + 0) * 1024 + (T)*64,                  \
                lwt + (H)*32768 + (BUF)*16384);                               \
    gload_lds16(gA0 + (size_t)((H)*128 + 64) * 1024 + (T)*64,                 \
                lwt + (H)*32768 + (BUF)*16384 + 8192);                        \
  } while (0)
#define STAGE_B(H, BUF, T)                                                    \
  do {                                                                        \
    gload_lds16(gB0 + (size_t)((H)*128 + 0) * 1024 + (T)*64,                  \
                lwt + (2 + (H)) * 32768 + (BUF)*16384);                       \
    gload_lds16(gB0 + (size_t)((H)*128 + 64) * 1024 + (T)*64,                 \
                lwt + (2 + (H)) * 32768 + (BUF)*16384 + 8192);                \
  } while (0)

  f32x4 acc[8][4] = {};
  bf16x8 aF[4][2], bF[2][2], bG[2][2];

  auto mfma16 = [&](int rb, int cb, bf16x8 (&bb)[2][2]) {
#pragma unroll
    for (int kk = 0; kk < 2; ++kk)
#pragma unroll
      for (int mi = 0; mi < 4; ++mi)
#pragma unroll
        for (int ni = 0; ni < 2; ++ni)
          acc[rb + mi][cb + ni] = __builtin_amdgcn_mfma_f32_16x16x32_bf16(
              aF[mi][kk], bb[ni][kk], acc[rb + mi][cb + ni], 0, 0, 0);
  };

#define SBAR() __builtin_amdgcn_sched_barrier(0)
#define BAR() __builtin_amdgcn_s_barrier()
#define LGKM0() asm volatile("s_waitcnt lgkmcnt(0)" ::: "memory")
#define LGKM8() asm volatile("s_waitcnt lgkmcnt(8)" ::: "memory")
  // GATE: 0 = vmcnt(4)+bar, 1 = vmcnt(0)+bar, 2 = none
#define TILE(T, BUF, OBUF, STHA, STHB, GATE)                                  \
  {                                                                           \
    /* P1: reads A-sub0(8)+B-lo(4); stage HA0(T+1)->OBUF; BAR; lgkm0; Q00 */  \
    _Pragma("unroll") for (int mi = 0; mi < 4; ++mi) {                        \
      aF[mi][0] = RDA(BUF, mi, 0); aF[mi][1] = RDA(BUF, mi, 1);               \
    }                                                                         \
    _Pragma("unroll") for (int ni = 0; ni < 2; ++ni) {                        \
      bF[ni][0] = RDB(BUF, ni, 0); bF[ni][1] = RDB(BUF, ni, 1);               \
    }                                                                         \
    if (STHA) STAGE_A(0, OBUF, (T) + 1);                                      \
    LGKM8(); SBAR(); BAR(); SBAR();                                           \
    LGKM0(); SBAR();                                                          \
    __builtin_amdgcn_s_setprio(1);                                            \
    mfma16(0, 0, bF);                                                         \
    __builtin_amdgcn_s_setprio(0);                                            \
    /* P2: reads B-hi(4); stage HA1(T+1)->OBUF; BAR; lgkm0; Q01 */            \
    _Pragma("unroll") for (int ni = 0; ni < 2; ++ni) {                        \
      bG[ni][0] = RDB(BUF, 2 + ni, 0); bG[ni][1] = RDB(BUF, 2 + ni, 1);       \
    }                                                                         \
    if (STHA) STAGE_A(1, OBUF, (T) + 1);                                      \
    SBAR(); BAR(); SBAR();                                                    \
    LGKM0(); SBAR();                                                          \
    __builtin_amdgcn_s_setprio(1);                                            \
    mfma16(0, 2, bG);                                                         \
    __builtin_amdgcn_s_setprio(0);                                            \
    /* P3: reads A-sub1(8); BAR; stage HB0(T+2)->BUF; lgkm0; Q11 */           \
    _Pragma("unroll") for (int mi = 0; mi < 4; ++mi) {                        \
      aF[mi][0] = RDA(BUF, 4 + mi, 0); aF[mi][1] = RDA(BUF, 4 + mi, 1);       \
    }                                                                         \
    SBAR(); BAR(); SBAR();                                                    \
    if (STHB) STAGE_B(0, BUF, (T) + 2);                                       \
    SBAR();                                                                   \
    LGKM0(); SBAR();                                                          \
    __builtin_amdgcn_s_setprio(1);                                            \
    mfma16(4, 2, bG);                                                         \
    __builtin_amdgcn_s_setprio(0);                                            \
    /* P4: stage HB1(T+2); counted gate; BAR; Q10 (registers only) */         \
    if (STHB) STAGE_B(1, BUF, (T) + 2);                                       \
    SBAR();                                                                   \
    if ((GATE) == 0) asm volatile("s_waitcnt vmcnt(4)" ::: "memory");         \
    else if ((GATE) == 1) asm volatile("s_waitcnt vmcnt(0)" ::: "memory");    \
    if ((GATE) != 2) BAR();                                                   \
    SBAR();                                                                   \
    __builtin_amdgcn_s_setprio(1);                                            \
    mfma16(4, 0, bF);                                                         \
    __builtin_amdgcn_s_setprio(0);                                            \
  }

  // prologue: A(0),B(0) -> buf0; B(1) -> buf1 (12 loads); gate first 8
  STAGE_A(0, 0, 0); STAGE_A(1, 0, 0);
  STAGE_B(0, 0, 0); STAGE_B(1, 0, 0);
  STAGE_B(0, 1, 1); STAGE_B(1, 1, 1);
  asm volatile("s_waitcnt vmcnt(4)" ::: "memory");
  BAR();

#pragma unroll 1
  for (int u = 0; u < 7; ++u) {
    TILE(2 * u, 0, 1, 1, 1, 0);
    TILE(2 * u + 1, 1, 0, 1, 1, 0);
  }
  TILE(14, 0, 1, 1, 0, 1);   // stage HA(15) only; drain to 0
  TILE(15, 1, 0, 0, 0, 2);   // final tile: no stages, no gate

#undef TILE
#undef SBAR
#undef BAR
#undef LGKM0
#undef LGKM8
#undef RDA
#undef RDB
#undef STAGE_A
#undef STAGE_B

  // ---- R12 epilogue: LDS-bounce transpose -> coalesced vector stores ----
  // acc[mi][ni][j]: C row = row0 + wm*128 + mi*16 + kl*4 + j,
  //                 C col = col0 + wn*64 + ni*16 + rl.
  // Per mi: dump the 32x256 f32 slab into eld[32][264] (pad 264 -> max
  // 2-way write conflict, conflict-free b128 reads), then thread t
  // (r=t>>4, cgrp=t&15) stores 4 vectors at cols cgrp*4 + i*64 (16-lane
  // groups write 256B contiguous).
  float* eld = (float*)&lds[0][0][0];  // 32*264*4 = 33.8 KB, free now
  __syncthreads();                     // all waves done with K-loop LDS
#pragma unroll 1
  for (int mi = 0; mi < 8; ++mi) {
#pragma unroll
    for (int ni = 0; ni < 4; ++ni)
#pragma unroll
      for (int j = 0; j < 4; ++j)
        eld[(wm * 16 + kl * 4 + j) * 264 + wn * 64 + ni * 16 + rl] =
            acc[mi][ni][j];
    __syncthreads();
    const int r = tid >> 4;      // 0..31
    const int cgrp = tid & 15;   // 0..15
    const size_t crow = (size_t)(row0 + (r >> 4) * 128 + mi * 16 + (r & 15));
#pragma unroll
    for (int i = 0; i < 4; ++i) {
      f32x4 v = *(const f32x4*)&eld[r * 264 + cgrp * 4 + i * 64];
      if constexpr (sizeof(OutT) == 2) {
        u16x4 o;
        o[0] = f2bf(v[0]); o[1] = f2bf(v[1]); o[2] = f2bf(v[2]); o[3] = f2bf(v[3]);
        *(u16x4*)&Cb[crow * 1024 + cgrp * 4 + i * 64] = o;
      } else {
        *(f32x4*)&Cb[crow * 1024 + cgrp * 4 + i * 64] = v;
      }
    }
    __syncthreads();
  }
}

// ---------------- merged softmax+transpose: z=0 key (rows), z=1 query (cols)
__global__ __launch_bounds__(256) void sm_both(const u16* __restrict__ Kp,
                                               const u16* __restrict__ Qp,
                                               u16* __restrict__ KT,
                                               u16* __restrict__ QT) {
  const int b = blockIdx.y;
  const int tid = threadIdx.x, lane = tid & 63, w = tid >> 6;
  __shared__ float red[32][64];   // partial max
  __shared__ float red2[32][64];  // partial sum
  __shared__ float cmax[64], cinv[64];
  __shared__ u16 Tl[64][72];

  if (blockIdx.z == 0) {
    // ---- key: softmax over d (rows), write transposed KT[b,d,n] ----
    const int n0 = blockIdx.x * 64;
    const u16* base = Kp + ((size_t)b * N_ + n0) * D_;
    for (int i = 0; i < 16; ++i) {
      const int r = w * 16 + i;
      const u16x8* rp = (const u16x8*)(base + (size_t)r * D_ + lane * 16);
      u16x8 v0 = rp[0], v1 = rp[1];
      float f[16];
#pragma unroll
      for (int j = 0; j < 8; ++j) { f[j] = bf2f(v0[j]); f[8 + j] = bf2f(v1[j]); }
      float m = -1e30f;
#pragma unroll
      for (int j = 0; j < 16; ++j) m = fmaxf(m, f[j]);
      for (int off = 32; off; off >>= 1) m = fmaxf(m, __shfl_xor(m, off));
      float s = 0.f;
#pragma unroll
      for (int j = 0; j < 16; ++j) s += __expf(f[j] - m);
      for (int off = 32; off; off >>= 1) s += __shfl_xor(s, off);
      if (lane == 0) { cmax[r] = m; cinv[r] = 1.f / s; }
    }
    __syncthreads();
    for (int ct = 0; ct < 16; ++ct) {
      const int r = tid >> 2, cb = (tid & 3) * 16;
      const u16x8* rp = (const u16x8*)(base + (size_t)r * D_ + ct * 64 + cb);
      u16x8 v0 = rp[0], v1 = rp[1];
      const float m = cmax[r], inv = cinv[r];
#pragma unroll
      for (int j = 0; j < 8; ++j) {
        Tl[r][cb + j] = f2bf(__expf(bf2f(v0[j]) - m) * inv);
        Tl[r][cb + 8 + j] = f2bf(__expf(bf2f(v1[j]) - m) * inv);
      }
      __syncthreads();
      const int c = tid >> 2, nb = (tid & 3) * 16;
      u16x8 o0, o1;
#pragma unroll
      for (int e = 0; e < 8; ++e) { o0[e] = Tl[nb + e][c]; o1[e] = Tl[nb + 8 + e][c]; }
      u16x8* op = (u16x8*)(KT + ((size_t)b * D_ + ct * 64 + c) * N_ + n0 + nb);
      op[0] = o0; op[1] = o1;
      __syncthreads();
    }
  } else {
    // ---- query: softmax over n (cols), write transposed QT[b,d,n] ----
    const int d0 = blockIdx.x * 64;
    const u16* base = Qp + (size_t)b * N_ * D_;
    // phase 1: vectorized online max/sum; stripe = 32-row band, oct = 8-col
    const int stripe = w * 8 + (lane >> 3), oct = lane & 7;
    float m[8], s[8];
#pragma unroll
    for (int j = 0; j < 8; ++j) { m[j] = -1e30f; s[j] = 0.f; }
    for (int i = 0; i < 32; ++i) {
      const int n = stripe * 32 + i;
      u16x8 v = *(const u16x8*)(base + (size_t)n * D_ + d0 + oct * 8);
#pragma unroll
      for (int j = 0; j < 8; ++j) {
        const float x = bf2f(v[j]);
        const float nm = fmaxf(m[j], x);
        s[j] = s[j] * __expf(m[j] - nm) + __expf(x - nm);
        m[j] = nm;
      }
    }
#pragma unroll
    for (int j = 0; j < 8; ++j) {
      red[stripe][oct * 8 + j] = m[j];
      red2[stripe][oct * 8 + j] = s[j];
    }
    __syncthreads();
    if (tid < 64) {
      float M = red[0][tid];
      for (int k2 = 1; k2 < 32; ++k2) M = fmaxf(M, red[k2][tid]);
      float S = 0.f;
      for (int k2 = 0; k2 < 32; ++k2) S += red2[k2][tid] * __expf(red[k2][tid] - M);
      cmax[tid] = M; cinv[tid] = 1.f / S;
    }
    __syncthreads();
    for (int nt = 0; nt < 16; ++nt) {
      const int r = tid >> 2, cb = (tid & 3) * 16;
      const u16x8* rp = (const u16x8*)(base + (size_t)(nt * 64 + r) * D_ + d0 + cb);
      u16x8 v0 = rp[0], v1 = rp[1];
#pragma unroll
      for (int j = 0; j < 8; ++j) {
        Tl[r][cb + j] = f2bf(__expf(bf2f(v0[j]) - cmax[cb + j]) * cinv[cb + j]);
        Tl[r][cb + 8 + j] =
            f2bf(__expf(bf2f(v1[j]) - cmax[cb + 8 + j]) * cinv[cb + 8 + j]);
      }
      __syncthreads();
      const int c = tid >> 2, nb = (tid & 3) * 16;
      u16x8 o0, o1;
#pragma unroll
      for (int e = 0; e < 8; ++e) { o0[e] = Tl[nb + e][c]; o1[e] = Tl[nb + 8 + e][c]; }
      u16x8* op = (u16x8*)(QT + ((size_t)b * D_ + d0 + c) * N_ + nt * 64 + nb);
      op[0] = o0; op[1] = o1;
      __syncthreads();
    }
  }
}

extern "C" void kernel_launch(void* const* d_in, const int* in_sizes, int n_in,
                              void* d_out, int out_size, void* d_ws, size_t ws_size,
                              hipStream_t stream) {
  const float* x = (const float*)d_in[0];
  const float* Wk = (const float*)d_in[1];
  const float* Wq = (const float*)d_in[2];
  const float* Wv = (const float*)d_in[3];
  const float* Wr = (const float*)d_in[4];
  float* out = (float*)d_out;
  char* ws = (char*)d_ws;
  const size_t MB = 1ull << 20;

  u16* Xb  = (u16*)(ws + 0 * MB);
  u16* KT  = (u16*)(ws + 0 * MB);
  u16* Wkb = (u16*)(ws + 32 * MB);   // [Wk;Wq;Wv;Wr] contiguous
  u16* Wrb = (u16*)(ws + 38 * MB);
  u16* Kp  = (u16*)(ws + 40 * MB);   // Kp/Qp/V each 32 MB apart (SPLITC routing)
  u16* St  = (u16*)(ws + 40 * MB);
  u16* Qp  = (u16*)(ws + 72 * MB);
  u16* Att = (u16*)(ws + 72 * MB);
  u16* V   = (u16*)(ws + 104 * MB);
  u16* QT  = (u16*)(ws + 136 * MB);

  cast_all<<<2048, 256, 0, stream>>>(x, Wk, Wq, Wv, Wr, Xb, Wkb);

  // merged projections: (16384 x 3072) = Xb @ [Wk;Wq;Wv]^T -> 64x12 = 768 blocks
  gemm_bt256<u16, true><<<768, 512, 0, stream>>>(Xb, Wkb, Kp, 0, 0, 0, 12, 768);

  // key + query softmax/transpose in one dispatch (z selects path)
  sm_both<<<dim3(16, B_, 2), 256, 0, stream>>>(Kp, Qp, KT, QT);

  const long long sNN = (long long)N_ * D_;
  // St[b,d',d] = sum_n QT[b,d',n]*KT[b,d,n]: 16 batches x (4x4) = 256 blocks
  gemm_bt256<u16, false><<<256, 512, 0, stream>>>(QT, KT, St, sNN, sNN, sNN, 4, 16);
  // Att[b,m,d'] = sum_d V[b,m,d]*St[b,d',d]
  gemm_bt256<u16, false><<<256, 512, 0, stream>>>(V, St, Att, sNN, sNN, sNN, 4, 16);
  // out = Att @ Wr^T (fp32 epilogue)
  gemm_bt256<float, false><<<256, 512, 0, stream>>>(Att, Wrb, out, 0, 0, 0, 4, 256);
}

// Round 13
// 256.968 us; speedup vs baseline: 8.3350x; 8.3350x over previous
//
#include <hip/hip_runtime.h>

typedef unsigned short u16;
typedef unsigned int u32;
typedef __attribute__((ext_vector_type(4))) float f32x4;
typedef __attribute__((ext_vector_type(8))) short bf16x8;
typedef __attribute__((ext_vector_type(4))) u16 u16x4;
typedef __attribute__((ext_vector_type(8))) u16 u16x8;

#define B_ 16
#define N_ 1024
#define D_ 1024
#define BM 256
#define BN 256
#define BK 64
#define EPIT 260  // epilogue LDS pitch (floats): 4*260%32=16 -> <=2-way banks

__device__ __forceinline__ float bf2f(u16 v) {
  return __uint_as_float((u32)v << 16);
}
__device__ __forceinline__ u16 f2bf(float f) {
  u32 u = __float_as_uint(f);
  return (u16)((u + 0x7FFFu + ((u >> 16) & 1u)) >> 16);
}
__device__ __forceinline__ void gload_lds16(const void* g, void* l) {
  __builtin_amdgcn_global_load_lds(
      (const __attribute__((address_space(1))) void*)g,
      (__attribute__((address_space(3))) void*)l, 16, 0, 0);
}

// ---------------- merged cast: x (fp32->bf16) + 4 weights -> contiguous ----
__global__ __launch_bounds__(256) void cast_all(
    const float* __restrict__ x, const float* __restrict__ w0,
    const float* __restrict__ w1, const float* __restrict__ w2,
    const float* __restrict__ w3, u16* __restrict__ outx,
    u16* __restrict__ outw) {
  const int nx4 = (B_ * N_ * D_) / 4;          // 4M float4
  const int per = (D_ * D_) / 4;               // 256K float4 per weight
  const int tot = nx4 + 4 * per;
  const int stride = gridDim.x * blockDim.x;
  for (int i = blockIdx.x * blockDim.x + threadIdx.x; i < tot; i += stride) {
    float4 v;
    u16x4* dst;
    if (i < nx4) {
      v = ((const float4*)x)[i];
      dst = (u16x4*)outx + i;
    } else {
      const int k = i - nx4;
      const int w = k / per, r = k - w * per;
      const float* src = (w == 0) ? w0 : (w == 1) ? w1 : (w == 2) ? w2 : w3;
      v = ((const float4*)src)[r];
      dst = (u16x4*)outw + k;
    }
    u16x4 o;
    o[0] = f2bf(v.x); o[1] = f2bf(v.y); o[2] = f2bf(v.z); o[3] = f2bf(v.w);
    *dst = o;
  }
}

// ---------------- 256x256 8-wave bt-GEMM, 4 phases / 4 barriers per K-tile --
// C[i,j] = sum_k A[i,k]*B[j,k], K fixed = 1024 (16 K-tiles of BK=64).
// LDS: [region A0,A1,B0,B1 x 32KB][buf x 16KB]. Swizzle byte^=((row&7)<<4);
// kk half-select XOR-folded into precomputed base pointers (NEVER added —
// the R7-R9 NaN bug). Sync: barrier first, lgkmcnt(0) after (m201
// semantics); overwrite ledger as R11. Gate vmcnt(4) once per tile at P4.
// R13: epilogue mi-loop FULLY UNROLLED (R12's `#pragma unroll 1` made
// acc[mi] runtime-indexed -> 128-float scratch spill, rule #20: VGPR 88,
// FETCH 1.77GB). Pitch 264->260 (bank-conflict-free).
template <typename OutT, bool SPLITC>
__global__ __launch_bounds__(512, 2) void gemm_bt256(
    const u16* __restrict__ A, const u16* __restrict__ Bm, OutT* __restrict__ C,
    long long sA, long long sB, long long sC, int tx_n, int nb_per) {
  __shared__ u16 lds[4][2][128 * 64];  // [A0,A1,B0,B1][buf]
  const int tid = threadIdx.x;
  const int lane = tid & 63;
  const int wid = tid >> 6;
  const int wm = wid >> 2;   // 0..1 -> 128-row half
  const int wn = wid & 3;    // 0..3 -> 64-col group
  const int rl = lane & 15, kl = lane >> 4;

  // bijective XCD swizzle (nwg % 8 == 0 for all our grids)
  const int nwg = gridDim.x;
  const int orig = blockIdx.x;
  const int wgid = (orig & 7) * (nwg >> 3) + (orig >> 3);
  const int batch = wgid / nb_per;
  const int rem = wgid % nb_per;
  const int row0 = (rem / tx_n) * BM;
  const int col0 = (rem % tx_n) * BN;
  A += (long long)batch * sA;
  Bm += (long long)batch * sB;
  OutT* Cb;
  if constexpr (SPLITC) {
    Cb = C + (size_t)(col0 >> 10) * ((size_t)16384 * 1024) + (col0 & 1023);
  } else {
    Cb = C + (long long)batch * sC + col0;
  }

  const char* lb = (const char*)&lds[0][0][0];
  char* lwt = (char*)&lds[0][0][0] + tid * 16;

  // kk-resolved swizzled read bases (XOR fold, see header comment)
  const u32 mask = (u32)((rl & 7) << 4);
  const u32 cs0 = ((u32)(kl * 16)) ^ mask;        // kk=0 column bytes
  const u32 cs1 = ((u32)(64 + kl * 16)) ^ mask;   // kk=1 column bytes
  const char* pAk0 = lb + wm * 32768 + rl * 128 + cs0;
  const char* pAk1 = lb + wm * 32768 + rl * 128 + cs1;
  const char* pBk0 =
      lb + (2 + (wn >> 1)) * 32768 + (wn & 1) * 8192 + rl * 128 + cs0;
  const char* pBk1 =
      lb + (2 + (wn >> 1)) * 32768 + (wn & 1) * 8192 + rl * 128 + cs1;
#define RDA(BUF, MI, KK) \
  (*(const bf16x8*)(((KK) ? pAk1 : pAk0) + (BUF)*16384 + (MI)*2048))
#define RDB(BUF, NI, KK) \
  (*(const bf16x8*)(((KK) ? pBk1 : pBk0) + (BUF)*16384 + (NI)*2048))

  // staging: linear LDS dest, inverse-swizzled global source
  const int r0 = tid >> 3;
  const u32 li0 = (u32)(((tid & 7) * 16) ^ ((r0 & 7) << 4));
  const u16* gA0 = A + (size_t)(row0 + r0) * 1024 + (li0 >> 1);
  const u16* gB0 = Bm + (size_t)(col0 + r0) * 1024 + (li0 >> 1);
#define STAGE_A(H, BUF, T)                                                    \
  do {                                                                        \
    gload_lds16(gA0 + (size_t)((H)*128 + 0) * 1024 + (T)*64,                  \
                lwt + (H)*32768 + (BUF)*16384);                               \
    gload_lds16(gA0 + (size_t)((H)*128 + 64) * 1024 + (T)*64,                 \
                lwt + (H)*32768 + (BUF)*16384 + 8192);                        \
  } while (0)
#define STAGE_B(H, BUF, T)                                                    \
  do {                                                                        \
    gload_lds16(gB0 + (size_t)((H)*128 + 0) * 1024 + (T)*64,                  \
                lwt + (2 + (H)) * 32768 + (BUF)*16384);                       \
    gload_lds16(gB0 + (size_t)((H)*128 + 64) * 1024 + (T)*64,                 \
                lwt + (2 + (H)) * 32768 + (BUF)*16384 + 8192);                \
  } while (0)

  f32x4 acc[8][4] = {};
  bf16x8 aF[4][2], bF[2][2], bG[2][2];

  auto mfma16 = [&](int rb, int cb, bf16x8 (&bb)[2][2]) {
#pragma unroll
    for (int kk = 0; kk < 2; ++kk)
#pragma unroll
      for (int mi = 0; mi < 4; ++mi)
#pragma unroll
        for (int ni = 0; ni < 2; ++ni)
          acc[rb + mi][cb + ni] = __builtin_amdgcn_mfma_f32_16x16x32_bf16(
              aF[mi][kk], bb[ni][kk], acc[rb + mi][cb + ni], 0, 0, 0);
  };

#define SBAR() __builtin_amdgcn_sched_barrier(0)
#define BAR() __builtin_amdgcn_s_barrier()
#define LGKM0() asm volatile("s_waitcnt lgkmcnt(0)" ::: "memory")
#define LGKM8() asm volatile("s_waitcnt lgkmcnt(8)" ::: "memory")
  // GATE: 0 = vmcnt(4)+bar, 1 = vmcnt(0)+bar, 2 = none
#define TILE(T, BUF, OBUF, STHA, STHB, GATE)                                  \
  {                                                                           \
    /* P1: reads A-sub0(8)+B-lo(4); stage HA0(T+1)->OBUF; BAR; lgkm0; Q00 */  \
    _Pragma("unroll") for (int mi = 0; mi < 4; ++mi) {                        \
      aF[mi][0] = RDA(BUF, mi, 0); aF[mi][1] = RDA(BUF, mi, 1);               \
    }                                                                         \
    _Pragma("unroll") for (int ni = 0; ni < 2; ++ni) {                        \
      bF[ni][0] = RDB(BUF, ni, 0); bF[ni][1] = RDB(BUF, ni, 1);               \
    }                                                                         \
    if (STHA) STAGE_A(0, OBUF, (T) + 1);                                      \
    LGKM8(); SBAR(); BAR(); SBAR();                                           \
    LGKM0(); SBAR();                                                          \
    __builtin_amdgcn_s_setprio(1);                                            \
    mfma16(0, 0, bF);                                                         \
    __builtin_amdgcn_s_setprio(0);                                            \
    /* P2: reads B-hi(4); stage HA1(T+1)->OBUF; BAR; lgkm0; Q01 */            \
    _Pragma("unroll") for (int ni = 0; ni < 2; ++ni) {                        \
      bG[ni][0] = RDB(BUF, 2 + ni, 0); bG[ni][1] = RDB(BUF, 2 + ni, 1);       \
    }                                                                         \
    if (STHA) STAGE_A(1, OBUF, (T) + 1);                                      \
    SBAR(); BAR(); SBAR();                                                    \
    LGKM0(); SBAR();                                                          \
    __builtin_amdgcn_s_setprio(1);                                            \
    mfma16(0, 2, bG);                                                         \
    __builtin_amdgcn_s_setprio(0);                                            \
    /* P3: reads A-sub1(8); BAR; stage HB0(T+2)->BUF; lgkm0; Q11 */           \
    _Pragma("unroll") for (int mi = 0; mi < 4; ++mi) {                        \
      aF[mi][0] = RDA(BUF, 4 + mi, 0); aF[mi][1] = RDA(BUF, 4 + mi, 1);       \
    }                                                                         \
    SBAR(); BAR(); SBAR();                                                    \
    if (STHB) STAGE_B(0, BUF, (T) + 2);                                       \
    SBAR();                                                                   \
    LGKM0(); SBAR();                                                          \
    __builtin_amdgcn_s_setprio(1);                                            \
    mfma16(4, 2, bG);                                                         \
    __builtin_amdgcn_s_setprio(0);                                            \
    /* P4: stage HB1(T+2); counted gate; BAR; Q10 (registers only) */         \
    if (STHB) STAGE_B(1, BUF, (T) + 2);                                       \
    SBAR();                                                                   \
    if ((GATE) == 0) asm volatile("s_waitcnt vmcnt(4)" ::: "memory");         \
    else if ((GATE) == 1) asm volatile("s_waitcnt vmcnt(0)" ::: "memory");    \
    if ((GATE) != 2) BAR();                                                   \
    SBAR();                                                                   \
    __builtin_amdgcn_s_setprio(1);                                            \
    mfma16(4, 0, bF);                                                         \
    __builtin_amdgcn_s_setprio(0);                                            \
  }

  // prologue: A(0),B(0) -> buf0; B(1) -> buf1 (12 loads); gate first 8
  STAGE_A(0, 0, 0); STAGE_A(1, 0, 0);
  STAGE_B(0, 0, 0); STAGE_B(1, 0, 0);
  STAGE_B(0, 1, 1); STAGE_B(1, 1, 1);
  asm volatile("s_waitcnt vmcnt(4)" ::: "memory");
  BAR();

#pragma unroll 1
  for (int u = 0; u < 7; ++u) {
    TILE(2 * u, 0, 1, 1, 1, 0);
    TILE(2 * u + 1, 1, 0, 1, 1, 0);
  }
  TILE(14, 0, 1, 1, 0, 1);   // stage HA(15) only; drain to 0
  TILE(15, 1, 0, 0, 0, 2);   // final tile: no stages, no gate

#undef TILE
#undef SBAR
#undef BAR
#undef LGKM0
#undef LGKM8
#undef RDA
#undef RDB
#undef STAGE_A
#undef STAGE_B

  // ---- epilogue: LDS-bounce transpose -> coalesced vector stores ----
  // FULLY UNROLLED over mi (static acc indices; rule #20).
  float* eld = (float*)&lds[0][0][0];  // 32*EPIT*4 bytes, free now
  __syncthreads();                     // all waves done with K-loop LDS
#pragma unroll
  for (int mi = 0; mi < 8; ++mi) {
#pragma unroll
    for (int ni = 0; ni < 4; ++ni)
#pragma unroll
      for (int j = 0; j < 4; ++j)
        eld[(wm * 16 + kl * 4 + j) * EPIT + wn * 64 + ni * 16 + rl] =
            acc[mi][ni][j];
    __syncthreads();
    const int r = tid >> 4;      // 0..31
    const int cgrp = tid & 15;   // 0..15
    const size_t crow = (size_t)(row0 + (r >> 4) * 128 + mi * 16 + (r & 15));
#pragma unroll
    for (int i = 0; i < 4; ++i) {
      f32x4 v = *(const f32x4*)&eld[r * EPIT + cgrp * 4 + i * 64];
      if constexpr (sizeof(OutT) == 2) {
        u16x4 o;
        o[0] = f2bf(v[0]); o[1] = f2bf(v[1]); o[2] = f2bf(v[2]); o[3] = f2bf(v[3]);
        *(u16x4*)&Cb[crow * 1024 + cgrp * 4 + i * 64] = o;
      } else {
        *(f32x4*)&Cb[crow * 1024 + cgrp * 4 + i * 64] = v;
      }
    }
    __syncthreads();
  }
}

// ---------------- merged softmax+transpose: z=0 key (rows), z=1 query (cols)
__global__ __launch_bounds__(256) void sm_both(const u16* __restrict__ Kp,
                                               const u16* __restrict__ Qp,
                                               u16* __restrict__ KT,
                                               u16* __restrict__ QT) {
  const int b = blockIdx.y;
  const int tid = threadIdx.x, lane = tid & 63, w = tid >> 6;
  __shared__ float red[32][64];   // partial max
  __shared__ float red2[32][64];  // partial sum
  __shared__ float cmax[64], cinv[64];
  __shared__ u16 Tl[64][72];

  if (blockIdx.z == 0) {
    // ---- key: softmax over d (rows), write transposed KT[b,d,n] ----
    const int n0 = blockIdx.x * 64;
    const u16* base = Kp + ((size_t)b * N_ + n0) * D_;
    for (int i = 0; i < 16; ++i) {
      const int r = w * 16 + i;
      const u16x8* rp = (const u16x8*)(base + (size_t)r * D_ + lane * 16);
      u16x8 v0 = rp[0], v1 = rp[1];
      float f[16];
#pragma unroll
      for (int j = 0; j < 8; ++j) { f[j] = bf2f(v0[j]); f[8 + j] = bf2f(v1[j]); }
      float m = -1e30f;
#pragma unroll
      for (int j = 0; j < 16; ++j) m = fmaxf(m, f[j]);
      for (int off = 32; off; off >>= 1) m = fmaxf(m, __shfl_xor(m, off));
      float s = 0.f;
#pragma unroll
      for (int j = 0; j < 16; ++j) s += __expf(f[j] - m);
      for (int off = 32; off; off >>= 1) s += __shfl_xor(s, off);
      if (lane == 0) { cmax[r] = m; cinv[r] = 1.f / s; }
    }
    __syncthreads();
    for (int ct = 0; ct < 16; ++ct) {
      const int r = tid >> 2, cb = (tid & 3) * 16;
      const u16x8* rp = (const u16x8*)(base + (size_t)r * D_ + ct * 64 + cb);
      u16x8 v0 = rp[0], v1 = rp[1];
      const float m = cmax[r], inv = cinv[r];
#pragma unroll
      for (int j = 0; j < 8; ++j) {
        Tl[r][cb + j] = f2bf(__expf(bf2f(v0[j]) - m) * inv);
        Tl[r][cb + 8 + j] = f2bf(__expf(bf2f(v1[j]) - m) * inv);
      }
      __syncthreads();
      const int c = tid >> 2, nb = (tid & 3) * 16;
      u16x8 o0, o1;
#pragma unroll
      for (int e = 0; e < 8; ++e) { o0[e] = Tl[nb + e][c]; o1[e] = Tl[nb + 8 + e][c]; }
      u16x8* op = (u16x8*)(KT + ((size_t)b * D_ + ct * 64 + c) * N_ + n0 + nb);
      op[0] = o0; op[1] = o1;
      __syncthreads();
    }
  } else {
    // ---- query: softmax over n (cols), write transposed QT[b,d,n] ----
    const int d0 = blockIdx.x * 64;
    const u16* base = Qp + (size_t)b * N_ * D_;
    // phase 1: vectorized online max/sum; stripe = 32-row band, oct = 8-col
    const int stripe = w * 8 + (lane >> 3), oct = lane & 7;
    float m[8], s[8];
#pragma unroll
    for (int j = 0; j < 8; ++j) { m[j] = -1e30f; s[j] = 0.f; }
    for (int i = 0; i < 32; ++i) {
      const int n = stripe * 32 + i;
      u16x8 v = *(const u16x8*)(base + (size_t)n * D_ + d0 + oct * 8);
#pragma unroll
      for (int j = 0; j < 8; ++j) {
        const float x = bf2f(v[j]);
        const float nm = fmaxf(m[j], x);
        s[j] = s[j] * __expf(m[j] - nm) + __expf(x - nm);
        m[j] = nm;
      }
    }
#pragma unroll
    for (int j = 0; j < 8; ++j) {
      red[stripe][oct * 8 + j] = m[j];
      red2[stripe][oct * 8 + j] = s[j];
    }
    __syncthreads();
    if (tid < 64) {
      float M = red[0][tid];
      for (int k2 = 1; k2 < 32; ++k2) M = fmaxf(M, red[k2][tid]);
      float S = 0.f;
      for (int k2 = 0; k2 < 32; ++k2) S += red2[k2][tid] * __expf(red[k2][tid] - M);
      cmax[tid] = M; cinv[tid] = 1.f / S;
    }
    __syncthreads();
    for (int nt = 0; nt < 16; ++nt) {
      const int r = tid >> 2, cb = (tid & 3) * 16;
      const u16x8* rp = (const u16x8*)(base + (size_t)(nt * 64 + r) * D_ + d0 + cb);
      u16x8 v0 = rp[0], v1 = rp[1];
#pragma unroll
      for (int j = 0; j < 8; ++j) {
        Tl[r][cb + j] = f2bf(__expf(bf2f(v0[j]) - cmax[cb + j]) * cinv[cb + j]);
        Tl[r][cb + 8 + j] =
            f2bf(__expf(bf2f(v1[j]) - cmax[cb + 8 + j]) * cinv[cb + 8 + j]);
      }
      __syncthreads();
      const int c = tid >> 2, nb = (tid & 3) * 16;
      u16x8 o0, o1;
#pragma unroll
      for (int e = 0; e < 8; ++e) { o0[e] = Tl[nb + e][c]; o1[e] = Tl[nb + 8 + e][c]; }
      u16x8* op = (u16x8*)(QT + ((size_t)b * D_ + d0 + c) * N_ + nt * 64 + nb);
      op[0] = o0; op[1] = o1;
      __syncthreads();
    }
  }
}

extern "C" void kernel_launch(void* const* d_in, const int* in_sizes, int n_in,
                              void* d_out, int out_size, void* d_ws, size_t ws_size,
                              hipStream_t stream) {
  const float* x = (const float*)d_in[0];
  const float* Wk = (const float*)d_in[1];
  const float* Wq = (const float*)d_in[2];
  const float* Wv = (const float*)d_in[3];
  const float* Wr = (const float*)d_in[4];
  float* out = (float*)d_out;
  char* ws = (char*)d_ws;
  const size_t MB = 1ull << 20;

  u16* Xb  = (u16*)(ws + 0 * MB);
  u16* KT  = (u16*)(ws + 0 * MB);
  u16* Wkb = (u16*)(ws + 32 * MB);   // [Wk;Wq;Wv;Wr] contiguous
  u16* Wrb = (u16*)(ws + 38 * MB);
  u16* Kp  = (u16*)(ws + 40 * MB);   // Kp/Qp/V each 32 MB apart (SPLITC routing)
  u16* St  = (u16*)(ws + 40 * MB);
  u16* Qp  = (u16*)(ws + 72 * MB);
  u16* Att = (u16*)(ws + 72 * MB);
  u16* V   = (u16*)(ws + 104 * MB);
  u16* QT  = (u16*)(ws + 136 * MB);

  cast_all<<<2048, 256, 0, stream>>>(x, Wk, Wq, Wv, Wr, Xb, Wkb);

  // merged projections: (16384 x 3072) = Xb @ [Wk;Wq;Wv]^T -> 64x12 = 768 blocks
  gemm_bt256<u16, true><<<768, 512, 0, stream>>>(Xb, Wkb, Kp, 0, 0, 0, 12, 768);

  // key + query softmax/transpose in one dispatch (z selects path)
  sm_both<<<dim3(16, B_, 2), 256, 0, stream>>>(Kp, Qp, KT, QT);

  const long long sNN = (long long)N_ * D_;
  // St[b,d',d] = sum_n QT[b,d',n]*KT[b,d,n]: 16 batches x (4x4) = 256 blocks
  gemm_bt256<u16, false><<<256, 512, 0, stream>>>(QT, KT, St, sNN, sNN, sNN, 4, 16);
  // Att[b,m,d'] = sum_d V[b,m,d]*St[b,d',d]
  gemm_bt256<u16, false><<<256, 512, 0, stream>>>(V, St, Att, sNN, sNN, sNN, 4, 16);
  // out = Att @ Wr^T (fp32 epilogue)
  gemm_bt256<float, false><<<256, 512, 0, stream>>>(Att, Wrb, out, 0, 0, 0, 4, 256);
}

// Round 14
// 256.161 us; speedup vs baseline: 8.3613x; 1.0031x over previous
//
#include <hip/hip_runtime.h>

typedef unsigned short u16;
typedef unsigned int u32;
typedef __attribute__((ext_vector_type(4))) float f32x4;
typedef __attribute__((ext_vector_type(8))) short bf16x8;
typedef __attribute__((ext_vector_type(4))) u16 u16x4;
typedef __attribute__((ext_vector_type(8))) u16 u16x8;

#define B_ 16
#define N_ 1024
#define D_ 1024
#define BM 256
#define BN 256
#define BK 64
#define EPIT 260  // epilogue LDS pitch (floats)

__device__ __forceinline__ float bf2f(u16 v) {
  return __uint_as_float((u32)v << 16);
}
__device__ __forceinline__ u16 f2bf(float f) {
  u32 u = __float_as_uint(f);
  return (u16)((u + 0x7FFFu + ((u >> 16) & 1u)) >> 16);
}
__device__ __forceinline__ void gload_lds16(const void* g, void* l) {
  __builtin_amdgcn_global_load_lds(
      (const __attribute__((address_space(1))) void*)g,
      (__attribute__((address_space(3))) void*)l, 16, 0, 0);
}

// ---------------- merged cast: x (fp32->bf16) + 4 weights -> contiguous ----
__global__ __launch_bounds__(256) void cast_all(
    const float* __restrict__ x, const float* __restrict__ w0,
    const float* __restrict__ w1, const float* __restrict__ w2,
    const float* __restrict__ w3, u16* __restrict__ outx,
    u16* __restrict__ outw) {
  const int nx4 = (B_ * N_ * D_) / 4;
  const int per = (D_ * D_) / 4;
  const int tot = nx4 + 4 * per;
  const int stride = gridDim.x * blockDim.x;
  for (int i = blockIdx.x * blockDim.x + threadIdx.x; i < tot; i += stride) {
    float4 v;
    u16x4* dst;
    if (i < nx4) {
      v = ((const float4*)x)[i];
      dst = (u16x4*)outx + i;
    } else {
      const int k = i - nx4;
      const int w = k / per, r = k - w * per;
      const float* src = (w == 0) ? w0 : (w == 1) ? w1 : (w == 2) ? w2 : w3;
      v = ((const float4*)src)[r];
      dst = (u16x4*)outw + k;
    }
    u16x4 o;
    o[0] = f2bf(v.x); o[1] = f2bf(v.y); o[2] = f2bf(v.z); o[3] = f2bf(v.w);
    *dst = o;
  }
}

// ---------------- 256x256 8-wave bt-GEMM, 2 barriers per K-tile -------------
// C[i,j] = sum_k A[i,k]*B[j,k], K fixed = 1024 (16 K-tiles of BK=64).
// LDS: [region A0,A1,B0,B1 x 32KB][buf x 16KB]. Swizzle byte^=((row&7)<<4);
// kk half-select XOR-folded into base pointers (NEVER added — R7-R9 bug).
// R14: 2 barriers/tile. Safety invariant: every wave executes lgkmcnt(0)
// (or counted wait covering the reads) before each MFMA cluster, hence
// before its next barrier arrival => its LDS reads are SAMPLED by the time
// any other wave passes that barrier. Ledger (A-regions wm-private; B read
// only in S1):
//  - HA0/HA1(T+1)->buf^1 issued in S1(T): buf^1 A-readers (tile T-1 S1/S2)
//    drained pre-Q11(T-1) < all arrivals at BAR-B(T-1) < issuer passed it.
//  - HB0/HB1(T+2)->buf issued after BAR-A(T): B(buf) readers (S1(T))
//    drained pre-Q00/Q01 < their arrival at BAR-A(T).
//  - Tile T's reads begin after BAR-B(T-1), whose per-wave vmcnt(4) gate
//    drained every wave's HA(T)+HB(T) DMA shares.
// Gate vmcnt(4) once per tile at BAR-B; tails: vmcnt(0)@T=14, none @T=15.
template <typename OutT, bool SPLITC>
__global__ __launch_bounds__(512, 2) void gemm_bt256(
    const u16* __restrict__ A, const u16* __restrict__ Bm, OutT* __restrict__ C,
    long long sA, long long sB, long long sC, int tx_n, int nb_per) {
  __shared__ u16 lds[4][2][128 * 64];  // [A0,A1,B0,B1][buf]
  const int tid = threadIdx.x;
  const int lane = tid & 63;
  const int wid = tid >> 6;
  const int wm = wid >> 2;
  const int wn = wid & 3;
  const int rl = lane & 15, kl = lane >> 4;

  const int nwg = gridDim.x;
  const int orig = blockIdx.x;
  const int wgid = (orig & 7) * (nwg >> 3) + (orig >> 3);
  const int batch = wgid / nb_per;
  const int rem = wgid % nb_per;
  const int row0 = (rem / tx_n) * BM;
  const int col0 = (rem % tx_n) * BN;
  A += (long long)batch * sA;
  Bm += (long long)batch * sB;
  OutT* Cb;
  if constexpr (SPLITC) {
    Cb = C + (size_t)(col0 >> 10) * ((size_t)16384 * 1024) + (col0 & 1023);
  } else {
    Cb = C + (long long)batch * sC + col0;
  }

  const char* lb = (const char*)&lds[0][0][0];
  char* lwt = (char*)&lds[0][0][0] + tid * 16;

  const u32 mask = (u32)((rl & 7) << 4);
  const u32 cs0 = ((u32)(kl * 16)) ^ mask;
  const u32 cs1 = ((u32)(64 + kl * 16)) ^ mask;
  const char* pAk0 = lb + wm * 32768 + rl * 128 + cs0;
  const char* pAk1 = lb + wm * 32768 + rl * 128 + cs1;
  const char* pBk0 =
      lb + (2 + (wn >> 1)) * 32768 + (wn & 1) * 8192 + rl * 128 + cs0;
  const char* pBk1 =
      lb + (2 + (wn >> 1)) * 32768 + (wn & 1) * 8192 + rl * 128 + cs1;
#define RDA(BUF, MI, KK) \
  (*(const bf16x8*)(((KK) ? pAk1 : pAk0) + (BUF)*16384 + (MI)*2048))
#define RDB(BUF, NI, KK) \
  (*(const bf16x8*)(((KK) ? pBk1 : pBk0) + (BUF)*16384 + (NI)*2048))

  const int r0 = tid >> 3;
  const u32 li0 = (u32)(((tid & 7) * 16) ^ ((r0 & 7) << 4));
  const u16* gA0 = A + (size_t)(row0 + r0) * 1024 + (li0 >> 1);
  const u16* gB0 = Bm + (size_t)(col0 + r0) * 1024 + (li0 >> 1);
#define STAGE_A(H, BUF, T)                                                    \
  do {                                                                        \
    gload_lds16(gA0 + (size_t)((H)*128 + 0) * 1024 + (T)*64,                  \
                lwt + (H)*32768 + (BUF)*16384);                               \
    gload_lds16(gA0 + (size_t)((H)*128 + 64) * 1024 + (T)*64,                 \
                lwt + (H)*32768 + (BUF)*16384 + 8192);                        \
  } while (0)
#define STAGE_B(H, BUF, T)                                                    \
  do {                                                                        \
    gload_lds16(gB0 + (size_t)((H)*128 + 0) * 1024 + (T)*64,                  \
                lwt + (2 + (H)) * 32768 + (BUF)*16384);                       \
    gload_lds16(gB0 + (size_t)((H)*128 + 64) * 1024 + (T)*64,                 \
                lwt + (2 + (H)) * 32768 + (BUF)*16384 + 8192);                \
  } while (0)

  f32x4 acc[8][4] = {};
  bf16x8 aF[4][2], bF[2][2], bG[2][2];

  auto mfma16 = [&](int rb, int cb, bf16x8 (&bb)[2][2]) {
#pragma unroll
    for (int kk = 0; kk < 2; ++kk)
#pragma unroll
      for (int mi = 0; mi < 4; ++mi)
#pragma unroll
        for (int ni = 0; ni < 2; ++ni)
          acc[rb + mi][cb + ni] = __builtin_amdgcn_mfma_f32_16x16x32_bf16(
              aF[mi][kk], bb[ni][kk], acc[rb + mi][cb + ni], 0, 0, 0);
  };

#define SBAR() __builtin_amdgcn_sched_barrier(0)
#define BAR() __builtin_amdgcn_s_barrier()
#define LGKM0() asm volatile("s_waitcnt lgkmcnt(0)" ::: "memory")
#define LGKM4() asm volatile("s_waitcnt lgkmcnt(4)" ::: "memory")
  // GATE: 0 = vmcnt(4)+bar, 1 = vmcnt(0)+bar, 2 = none
#define TILE(T, BUF, OBUF, STHA, STHB, GATE)                                  \
  {                                                                           \
    /* S1: reads aF0-3 + bF (12); pin; reads bG (4) + stage HA0/HA1(T+1); */  \
    /*     lgkm(4) -> Q00; lgkm(0) -> Q01.  No barrier in S1.            */   \
    _Pragma("unroll") for (int mi = 0; mi < 4; ++mi) {                        \
      aF[mi][0] = RDA(BUF, mi, 0); aF[mi][1] = RDA(BUF, mi, 1);               \
    }                                                                         \
    _Pragma("unroll") for (int ni = 0; ni < 2; ++ni) {                        \
      bF[ni][0] = RDB(BUF, ni, 0); bF[ni][1] = RDB(BUF, ni, 1);               \
    }                                                                         \
    SBAR();                                                                   \
    _Pragma("unroll") for (int ni = 0; ni < 2; ++ni) {                        \
      bG[ni][0] = RDB(BUF, 2 + ni, 0); bG[ni][1] = RDB(BUF, 2 + ni, 1);       \
    }                                                                         \
    if (STHA) { STAGE_A(0, OBUF, (T) + 1); STAGE_A(1, OBUF, (T) + 1); }       \
    SBAR();                                                                   \
    LGKM4(); SBAR();                                                          \
    __builtin_amdgcn_s_setprio(1);                                            \
    mfma16(0, 0, bF);                                                         \
    __builtin_amdgcn_s_setprio(0);                                            \
    SBAR();                                                                   \
    LGKM0(); SBAR();                                                          \
    __builtin_amdgcn_s_setprio(1);                                            \
    mfma16(0, 2, bG);                                                         \
    __builtin_amdgcn_s_setprio(0);                                            \
    /* S2: reads aF4-7; BAR-A; stage HB0(T+2); lgkm0 -> Q11; stage HB1; */    \
    /*     gate; BAR-B; Q10. */                                               \
    _Pragma("unroll") for (int mi = 0; mi < 4; ++mi) {                        \
      aF[mi][0] = RDA(BUF, 4 + mi, 0); aF[mi][1] = RDA(BUF, 4 + mi, 1);       \
    }                                                                         \
    SBAR(); BAR(); SBAR();                                                    \
    if (STHB) STAGE_B(0, BUF, (T) + 2);                                       \
    SBAR();                                                                   \
    LGKM0(); SBAR();                                                          \
    __builtin_amdgcn_s_setprio(1);                                            \
    mfma16(4, 2, bG);                                                         \
    __builtin_amdgcn_s_setprio(0);                                            \
    if (STHB) STAGE_B(1, BUF, (T) + 2);                                       \
    SBAR();                                                                   \
    if ((GATE) == 0) asm volatile("s_waitcnt vmcnt(4)" ::: "memory");         \
    else if ((GATE) == 1) asm volatile("s_waitcnt vmcnt(0)" ::: "memory");    \
    if ((GATE) != 2) BAR();                                                   \
    SBAR();                                                                   \
    __builtin_amdgcn_s_setprio(1);                                            \
    mfma16(4, 0, bF);                                                         \
    __builtin_amdgcn_s_setprio(0);                                            \
  }

  // prologue: HA(0),HB(0) -> buf0; HB(1) -> buf1 (12 loads); gate leaves
  // HB(1)'s 4 in flight... must be landed before tile1 -> drained at gate(0).
  STAGE_A(0, 0, 0); STAGE_A(1, 0, 0);
  STAGE_B(0, 0, 0); STAGE_B(1, 0, 0);
  STAGE_B(0, 1, 1); STAGE_B(1, 1, 1);
  asm volatile("s_waitcnt vmcnt(4)" ::: "memory");
  BAR();

#pragma unroll 1
  for (int u = 0; u < 7; ++u) {
    TILE(2 * u, 0, 1, 1, 1, 0);
    TILE(2 * u + 1, 1, 0, 1, 1, 0);
  }
  TILE(14, 0, 1, 1, 0, 1);   // stage HA(15) only; drain to 0
  TILE(15, 1, 0, 0, 0, 2);   // final tile: no stages, no gate

#undef TILE
#undef SBAR
#undef BAR
#undef LGKM0
#undef LGKM4
#undef RDA
#undef RDB
#undef STAGE_A
#undef STAGE_B

  // ---- epilogue: LDS-bounce transpose -> coalesced vector stores ----
  float* eld = (float*)&lds[0][0][0];
  __syncthreads();
#pragma unroll
  for (int mi = 0; mi < 8; ++mi) {
#pragma unroll
    for (int ni = 0; ni < 4; ++ni)
#pragma unroll
      for (int j = 0; j < 4; ++j)
        eld[(wm * 16 + kl * 4 + j) * EPIT + wn * 64 + ni * 16 + rl] =
            acc[mi][ni][j];
    __syncthreads();
    const int r = tid >> 4;
    const int cgrp = tid & 15;
    const size_t crow = (size_t)(row0 + (r >> 4) * 128 + mi * 16 + (r & 15));
#pragma unroll
    for (int i = 0; i < 4; ++i) {
      f32x4 v = *(const f32x4*)&eld[r * EPIT + cgrp * 4 + i * 64];
      if constexpr (sizeof(OutT) == 2) {
        u16x4 o;
        o[0] = f2bf(v[0]); o[1] = f2bf(v[1]); o[2] = f2bf(v[2]); o[3] = f2bf(v[3]);
        *(u16x4*)&Cb[crow * 1024 + cgrp * 4 + i * 64] = o;
      } else {
        *(f32x4*)&Cb[crow * 1024 + cgrp * 4 + i * 64] = v;
      }
    }
    __syncthreads();
  }
}

// ---------------- merged softmax+transpose: z=0 key (rows), z=1 query (cols)
__global__ __launch_bounds__(256) void sm_both(const u16* __restrict__ Kp,
                                               const u16* __restrict__ Qp,
                                               u16* __restrict__ KT,
                                               u16* __restrict__ QT) {
  const int b = blockIdx.y;
  const int tid = threadIdx.x, lane = tid & 63, w = tid >> 6;
  __shared__ float red[32][64];
  __shared__ float red2[32][64];
  __shared__ float cmax[64], cinv[64];
  __shared__ u16 Tl[64][72];

  if (blockIdx.z == 0) {
    const int n0 = blockIdx.x * 64;
    const u16* base = Kp + ((size_t)b * N_ + n0) * D_;
    for (int i = 0; i < 16; ++i) {
      const int r = w * 16 + i;
      const u16x8* rp = (const u16x8*)(base + (size_t)r * D_ + lane * 16);
      u16x8 v0 = rp[0], v1 = rp[1];
      float f[16];
#pragma unroll
      for (int j = 0; j < 8; ++j) { f[j] = bf2f(v0[j]); f[8 + j] = bf2f(v1[j]); }
      float m = -1e30f;
#pragma unroll
      for (int j = 0; j < 16; ++j) m = fmaxf(m, f[j]);
      for (int off = 32; off; off >>= 1) m = fmaxf(m, __shfl_xor(m, off));
      float s = 0.f;
#pragma unroll
      for (int j = 0; j < 16; ++j) s += __expf(f[j] - m);
      for (int off = 32; off; off >>= 1) s += __shfl_xor(s, off);
      if (lane == 0) { cmax[r] = m; cinv[r] = 1.f / s; }
    }
    __syncthreads();
    for (int ct = 0; ct < 16; ++ct) {
      const int r = tid >> 2, cb = (tid & 3) * 16;
      const u16x8* rp = (const u16x8*)(base + (size_t)r * D_ + ct * 64 + cb);
      u16x8 v0 = rp[0], v1 = rp[1];
      const float m = cmax[r], inv = cinv[r];
#pragma unroll
      for (int j = 0; j < 8; ++j) {
        Tl[r][cb + j] = f2bf(__expf(bf2f(v0[j]) - m) * inv);
        Tl[r][cb + 8 + j] = f2bf(__expf(bf2f(v1[j]) - m) * inv);
      }
      __syncthreads();
      const int c = tid >> 2, nb = (tid & 3) * 16;
      u16x8 o0, o1;
#pragma unroll
      for (int e = 0; e < 8; ++e) { o0[e] = Tl[nb + e][c]; o1[e] = Tl[nb + 8 + e][c]; }
      u16x8* op = (u16x8*)(KT + ((size_t)b * D_ + ct * 64 + c) * N_ + n0 + nb);
      op[0] = o0; op[1] = o1;
      __syncthreads();
    }
  } else {
    const int d0 = blockIdx.x * 64;
    const u16* base = Qp + (size_t)b * N_ * D_;
    const int stripe = w * 8 + (lane >> 3), oct = lane & 7;
    float m[8], s[8];
#pragma unroll
    for (int j = 0; j < 8; ++j) { m[j] = -1e30f; s[j] = 0.f; }
    for (int i = 0; i < 32; ++i) {
      const int n = stripe * 32 + i;
      u16x8 v = *(const u16x8*)(base + (size_t)n * D_ + d0 + oct * 8);
#pragma unroll
      for (int j = 0; j < 8; ++j) {
        const float x = bf2f(v[j]);
        const float nm = fmaxf(m[j], x);
        s[j] = s[j] * __expf(m[j] - nm) + __expf(x - nm);
        m[j] = nm;
      }
    }
#pragma unroll
    for (int j = 0; j < 8; ++j) {
      red[stripe][oct * 8 + j] = m[j];
      red2[stripe][oct * 8 + j] = s[j];
    }
    __syncthreads();
    if (tid < 64) {
      float M = red[0][tid];
      for (int k2 = 1; k2 < 32; ++k2) M = fmaxf(M, red[k2][tid]);
      float S = 0.f;
      for (int k2 = 0; k2 < 32; ++k2) S += red2[k2][tid] * __expf(red[k2][tid] - M);
      cmax[tid] = M; cinv[tid] = 1.f / S;
    }
    __syncthreads();
    for (int nt = 0; nt < 16; ++nt) {
      const int r = tid >> 2, cb = (tid & 3) * 16;
      const u16x8* rp = (const u16x8*)(base + (size_t)(nt * 64 + r) * D_ + d0 + cb);
      u16x8 v0 = rp[0], v1 = rp[1];
#pragma unroll
      for (int j = 0; j < 8; ++j) {
        Tl[r][cb + j] = f2bf(__expf(bf2f(v0[j]) - cmax[cb + j]) * cinv[cb + j]);
        Tl[r][cb + 8 + j] =
            f2bf(__expf(bf2f(v1[j]) - cmax[cb + 8 + j]) * cinv[cb + 8 + j]);
      }
      __syncthreads();
      const int c = tid >> 2, nb = (tid & 3) * 16;
      u16x8 o0, o1;
#pragma unroll
      for (int e = 0; e < 8; ++e) { o0[e] = Tl[nb + e][c]; o1[e] = Tl[nb + 8 + e][c]; }
      u16x8* op = (u16x8*)(QT + ((size_t)b * D_ + d0 + c) * N_ + nt * 64 + nb);
      op[0] = o0; op[1] = o1;
      __syncthreads();
    }
  }
}

extern "C" void kernel_launch(void* const* d_in, const int* in_sizes, int n_in,
                              void* d_out, int out_size, void* d_ws, size_t ws_size,
                              hipStream_t stream) {
  const float* x = (const float*)d_in[0];
  const float* Wk = (const float*)d_in[1];
  const float* Wq = (const float*)d_in[2];
  const float* Wv = (const float*)d_in[3];
  const float* Wr = (const float*)d_in[4];
  float* out = (float*)d_out;
  char* ws = (char*)d_ws;
  const size_t MB = 1ull << 20;

  u16* Xb  = (u16*)(ws + 0 * MB);
  u16* KT  = (u16*)(ws + 0 * MB);
  u16* Wkb = (u16*)(ws + 32 * MB);
  u16* Wrb = (u16*)(ws + 38 * MB);
  u16* Kp  = (u16*)(ws + 40 * MB);
  u16* St  = (u16*)(ws + 40 * MB);
  u16* Qp  = (u16*)(ws + 72 * MB);
  u16* Att = (u16*)(ws + 72 * MB);
  u16* V   = (u16*)(ws + 104 * MB);
  u16* QT  = (u16*)(ws + 136 * MB);

  cast_all<<<2048, 256, 0, stream>>>(x, Wk, Wq, Wv, Wr, Xb, Wkb);

  // merged projections: (16384 x 3072) = Xb @ [Wk;Wq;Wv]^T -> 768 blocks
  gemm_bt256<u16, true><<<768, 512, 0, stream>>>(Xb, Wkb, Kp, 0, 0, 0, 12, 768);

  // key + query softmax/transpose in one dispatch (z selects path)
  sm_both<<<dim3(16, B_, 2), 256, 0, stream>>>(Kp, Qp, KT, QT);

  const long long sNN = (long long)N_ * D_;
  gemm_bt256<u16, false><<<256, 512, 0, stream>>>(QT, KT, St, sNN, sNN, sNN, 4, 16);
  gemm_bt256<u16, false><<<256, 512, 0, stream>>>(V, St, Att, sNN, sNN, sNN, 4, 16);
  gemm_bt256<float, false><<<256, 512, 0, stream>>>(Att, Wrb, out, 0, 0, 0, 4, 256);
}